// Round 11
// baseline (171.472 us; speedup 1.0000x reference)
//
#include <hip/hip_runtime.h>
#include <hip/hip_bf16.h>
#include <stdint.h>

#define D_MODEL 1024

typedef __attribute__((ext_vector_type(4))) float  f32x4;
typedef __attribute__((ext_vector_type(8))) __bf16 bf16x8;
typedef __attribute__((ext_vector_type(8))) unsigned short u16x8;
typedef __attribute__((ext_vector_type(4))) unsigned short u16x4;

// ---------- helpers ----------

__device__ __forceinline__ unsigned order_map(float x) {
    unsigned u = __float_as_uint(x);
    return (u & 0x80000000u) ? ~u : (u | 0x80000000u);
}
__device__ __forceinline__ float order_unmap(unsigned m) {
    unsigned b = (m & 0x80000000u) ? (m & 0x7fffffffu) : ~m;
    return __uint_as_float(b);
}
__device__ __forceinline__ unsigned short f2bf(float f) {
    unsigned u = __float_as_uint(f);
    u += 0x7fffu + ((u >> 16) & 1u);
    return (unsigned short)(u >> 16);
}

// ---------- prelude kernels ----------

__global__ void init_u32(unsigned* __restrict__ p, int n) {
    int i = blockIdx.x * blockDim.x + threadIdx.x;
    if (i < n) p[i] = 0u;
}

// atomic column max (used for w; fallback for x if ws too small)
__global__ void colmax_kernel(const float* __restrict__ src, int rows_per_slab,
                              int cols, unsigned* __restrict__ out_u) {
    int k = blockIdx.x * blockDim.x + threadIdx.x;
    const float* p = src + (size_t)blockIdx.y * rows_per_slab * cols + k;
    float m = -__builtin_inff();
#pragma unroll 4
    for (int r = 0; r < rows_per_slab; ++r)
        m = fmaxf(m, p[(size_t)r * cols]);
    atomicMax(&out_u[k], order_map(m));
}

// R11: read-only column-max partials of x (Xb eliminated — GEMM reads raw x)
#define CC_ROWS 16
__global__ __launch_bounds__(256)
void colmax_part(const float* __restrict__ x, float* __restrict__ partial) {
    int c4 = threadIdx.x * 4;
    size_t base = (size_t)blockIdx.x * CC_ROWS * D_MODEL + c4;
    f32x4 m4 = {-__builtin_inff(), -__builtin_inff(), -__builtin_inff(), -__builtin_inff()};
#pragma unroll 8
    for (int r = 0; r < CC_ROWS; ++r) {
        f32x4 v = *reinterpret_cast<const f32x4*>(&x[base + (size_t)r * D_MODEL]);
#pragma unroll
        for (int e = 0; e < 4; ++e) m4[e] = fmaxf(m4[e], v[e]);
    }
    *reinterpret_cast<f32x4*>(&partial[(size_t)blockIdx.x * D_MODEL + c4]) = m4;
}

__global__ void reduce_partial(const float* __restrict__ partial,
                               unsigned* __restrict__ ma_u) {
    int col  = blockIdx.x * 256 + threadIdx.x;
    int b0   = blockIdx.y * 64;
    float m = -__builtin_inff();
#pragma unroll 8
    for (int i = 0; i < 64; ++i)
        m = fmaxf(m, partial[(size_t)(b0 + i) * D_MODEL + col]);
    atomicMax(&ma_u[col], order_map(m));
}

__global__ void scale_kernel(const unsigned* __restrict__ ma_u,
                             const unsigned* __restrict__ mw_u,
                             float* __restrict__ s) {
    int k = blockIdx.x * blockDim.x + threadIdx.x;
    if (k < D_MODEL) {
        float ma = order_unmap(ma_u[k]);
        float mw = order_unmap(mw_u[k]);
        s[k] = sqrtf(ma) / sqrtf(mw);   // ALPHA = 0.5
    }
}

__global__ void build_w_kernel(const float* __restrict__ W, const float* __restrict__ s,
                               unsigned short* __restrict__ Wp) {
    int j  = blockIdx.x;
    int k4 = threadIdx.x * 4;
    float sj = s[j];
    f32x4 w  = *reinterpret_cast<const f32x4*>(&W[(size_t)j * D_MODEL + k4]);
    f32x4 sk = *reinterpret_cast<const f32x4*>(&s[k4]);
    u16x4 o;
#pragma unroll
    for (int i = 0; i < 4; ++i) o[i] = f2bf(sj * w[i] / sk[i]);
    *reinterpret_cast<u16x4*>(&Wp[(size_t)j * D_MODEL + k4]) = o;
}

// ---------- GEMM: 256x256, 8 waves, BK=32, triple buffer (R9 skeleton) ----------
// R11: A read RAW f32 from x with on-the-fly f2bf (Xb pass eliminated).
// T14 split: A(t+2) global->regs issued at tile t (2-tile slack, alternating
// named reg sets apf0/apf1 — rule #20); convert+swizzled ds_write of A(t+1)
// at tile t (buffer free since t-2; barrier-ordered). B stays global_load_lds
// (proven R9 path). vmcnt: per tile 8 new ops (A 4 + B 4); compiler auto-waits
// the A-reg use; manual vmcnt(8) before barrier retires B(t+1) by FIFO.
#define GBM 256
#define GBN 256
#define GBK 32
#define GNT (D_MODEL / GBK)   // 32
#define BUF_SHORTS 8192       // 16 KB per matrix per buffer

__global__ __launch_bounds__(512, 2)
void gemm_main(const float* __restrict__ X,
               const unsigned short* __restrict__ Wp,
               const float* __restrict__ bias,
               float* __restrict__ out) {
    __shared__ __align__(16) unsigned short lds[6 * BUF_SHORTS];  // A:0-2, B:3-5 (96 KB)

    int flat  = blockIdx.x;
    int xcd   = flat & 7;
    int j     = flat >> 3;
    int col0  = (j & 3) * GBN;
    int row0  = ((xcd << 4) + (j >> 2)) * GBM;   // within-XCD x reuse (R8)

    int tid  = threadIdx.x;
    int wave = tid >> 6;
    int lane = tid & 63;
    int wr   = wave >> 2;
    int wc   = wave & 3;
    int l16  = lane & 15;
    int lq   = lane >> 4;
    // B staging (gload_lds, pre-swizzled source — rule #21, proven R9)
    int sline = lane >> 3;
    int slog  = (lane & 7) ^ sline;
    int sh    = slog >> 2;
    int sq    = slog & 3;
    // A reg-stage addressing: thread -> row ar, 16 floats at k-half akh
    int ar   = tid >> 1;
    int akh  = (tid & 1) * 16;
    int aline = tid >> 2;
    int as0   = (((tid >> 1) & 1) << 2) | ((tid & 1) << 1);
    int aoff0 = aline * 128 + (((as0    ) << 4) ^ ((aline & 7) << 4));
    int aoff1 = aline * 128 + (((as0 + 1) << 4) ^ ((aline & 7) << 4));

    f32x4 acc[8][4];
#pragma unroll
    for (int m = 0; m < 8; ++m)
#pragma unroll
        for (int n = 0; n < 4; ++n)
            acc[m][n] = (f32x4){0.f, 0.f, 0.f, 0.f};

    f32x4 apf0[4], apf1[4];

    auto issueA = [&](int t, f32x4 (&apf)[4]) {
        const float* gp = X + (size_t)(row0 + ar) * D_MODEL + t * GBK + akh;
#pragma unroll
        for (int i = 0; i < 4; ++i)
            apf[i] = *reinterpret_cast<const f32x4*>(gp + i * 4);
    };
    auto issueB = [&](int t, int b) {
        int k0 = t * GBK;
#pragma unroll
        for (int r = 0; r < 2; ++r) {
            int line = r * 64 + wave * 8 + sline;
            const unsigned short* g =
                Wp + (size_t)(col0 + 2 * line + sh) * D_MODEL + k0 + sq * 8;
            __builtin_amdgcn_global_load_lds(
                (const __attribute__((address_space(1))) void*)g,
                (__attribute__((address_space(3))) void*)&lds[(3 + b) * BUF_SHORTS + line * 64],
                16, 0, 0);
        }
    };
    auto convA = [&](f32x4 (&apf)[4], int b) {
        u16x8 v0, v1;
#pragma unroll
        for (int e = 0; e < 4; ++e) {
            v0[e]     = f2bf(apf[0][e]);
            v0[e + 4] = f2bf(apf[1][e]);
            v1[e]     = f2bf(apf[2][e]);
            v1[e + 4] = f2bf(apf[3][e]);
        }
        char* ab = (char*)&lds[b * BUF_SHORTS];
        *reinterpret_cast<u16x8*>(ab + aoff0) = v0;
        *reinterpret_cast<u16x8*>(ab + aoff1) = v1;
    };

    // prologue: issue tiles 0,1; convert+write A(0); B(0) landed; barrier
    issueA(0, apf0); issueB(0, 0);
    issueA(1, apf1); issueB(1, 1);
    convA(apf0, 0);                                      // compiler waits apf0 regs
    asm volatile("s_waitcnt vmcnt(8)" ::: "memory");     // retires B(0); A(1),B(1) in flight
    asm volatile("s_waitcnt lgkmcnt(0)" ::: "memory");
    __builtin_amdgcn_s_barrier();

    int c0 = 0, c1 = 1, c2 = 2;   // t%3, (t+1)%3, (t+2)%3

    auto body = [&](int t, f32x4 (&cur)[4], f32x4 (&nxt)[4]) {
        if (t + 2 < GNT) { issueA(t + 2, cur); issueB(t + 2, c2); }
        if (t + 1 < GNT) convA(nxt, c1);     // A(t+1) -> Abuf[c1] (free since t-2)

        const char* Ab = (const char*)&lds[c0 * BUF_SHORTS];
        const char* Bb = (const char*)&lds[(3 + c0) * BUF_SHORTS];

        bf16x8 bfr[4];
#pragma unroll
        for (int n = 0; n < 4; ++n) {
            int cc   = wc * 64 + n * 16 + l16;
            int line = cc >> 1;
            int o    = (((cc & 1) << 6) + (lq << 4)) ^ ((line & 7) << 4);
            bfr[n] = *reinterpret_cast<const bf16x8*>(Bb + line * 128 + o);
        }
        bf16x8 afr[8];
#pragma unroll
        for (int m = 0; m < 8; ++m) {
            int rr   = wr * 128 + m * 16 + l16;
            int line = rr >> 1;
            int o    = (((rr & 1) << 6) + (lq << 4)) ^ ((line & 7) << 4);
            afr[m] = *reinterpret_cast<const bf16x8*>(Ab + line * 128 + o);
        }

        __builtin_amdgcn_s_setprio(1);
#pragma unroll
        for (int m = 0; m < 8; ++m)
#pragma unroll
            for (int n = 0; n < 4; ++n)
                acc[m][n] = __builtin_amdgcn_mfma_f32_16x16x32_bf16(
                    afr[m], bfr[n], acc[m][n], 0, 0, 0);
        __builtin_amdgcn_s_setprio(0);

        if (t + 1 < GNT) {
            if (t + 2 < GNT) asm volatile("s_waitcnt vmcnt(8)" ::: "memory"); // B(t+1) done
            else             asm volatile("s_waitcnt vmcnt(0)" ::: "memory");
            asm volatile("s_waitcnt lgkmcnt(0)" ::: "memory");  // A ds_writes visible
            __builtin_amdgcn_s_barrier();
        }
        int tmp = c0; c0 = c1; c1 = c2; c2 = tmp;
    };

#pragma unroll 1
    for (int tt = 0; tt < GNT; tt += 2) {
        body(tt,     apf0, apf1);
        body(tt + 1, apf1, apf0);
    }

    // ---- epilogue: C/D col = lane&15, row = lq*4 + q ----
    int crow = row0 + wr * 128;
    int ccol = col0 + wc * 64;
#pragma unroll
    for (int n = 0; n < 4; ++n) {
        int col = ccol + n * 16 + l16;
        float b = bias[col];
#pragma unroll
        for (int m = 0; m < 8; ++m) {
            int r = crow + m * 16 + lq * 4;
#pragma unroll
            for (int q = 0; q < 4; ++q)
                out[(size_t)(r + q) * D_MODEL + col] = acc[m][n][q] + b;
        }
    }
}

// ---------- launch ----------

extern "C" void kernel_launch(void* const* d_in, const int* in_sizes, int n_in,
                              void* d_out, int out_size, void* d_ws, size_t ws_size,
                              hipStream_t stream) {
    const float* x    = (const float*)d_in[0];
    const float* w    = (const float*)d_in[1];
    const float* bias = (const float*)d_in[2];
    float* out        = (float*)d_out;
    const int N       = in_sizes[0] / D_MODEL;   // 32768

    // ws: [0,4K) ma_u | [4K,8K) mw_u | [8K,12K) s | [16K,16K+2M) Wp | part (8 MB)
    char* ws               = (char*)d_ws;
    unsigned*       ma_u   = (unsigned*)(ws);
    unsigned*       mw_u   = (unsigned*)(ws + 4096);
    float*          s      = (float*)(ws + 8192);
    unsigned short* Wp     = (unsigned short*)(ws + 16384);
    const int nPart        = N / CC_ROWS;   // 2048
    float*          part   = (float*)(ws + 16384 + (size_t)D_MODEL * D_MODEL * 2);

    size_t need = 16384 + (size_t)D_MODEL * D_MODEL * 2 + (size_t)nPart * D_MODEL * 4;
    bool use_part = ws_size >= need;

    init_u32<<<8, 256, 0, stream>>>((unsigned*)ws, 2048);

    if (use_part) {
        colmax_part<<<nPart, 256, 0, stream>>>(x, part);
        reduce_partial<<<dim3(D_MODEL / 256, nPart / 64), 256, 0, stream>>>(part, ma_u);
    } else {
        colmax_kernel<<<dim3(D_MODEL / 256, 64), 256, 0, stream>>>(x, N / 64, D_MODEL, ma_u);
    }
    colmax_kernel<<<dim3(D_MODEL / 256, 16), 256, 0, stream>>>(w, D_MODEL / 16, D_MODEL, mw_u);
    scale_kernel<<<D_MODEL / 256, 256, 0, stream>>>(ma_u, mw_u, s);
    build_w_kernel<<<D_MODEL, 256, 0, stream>>>(w, s, Wp);

    int nblk = (N / GBM) * (D_MODEL / GBN);   // 512
    gemm_main<<<nblk, 512, 0, stream>>>(x, Wp, bias, out);
}